// Round 1
// baseline (2252.742 us; speedup 1.0000x reference)
//
#include <hip/hip_runtime.h>
#include <hip/hip_bf16.h>
#include <math.h>

#define NEG_SLOPE 0.2f
#define EPS 1e-16f

__device__ __forceinline__ float leaky(float x) {
    return x > 0.f ? x : NEG_SLOPE * x;
}

// float atomic max via int-max (positive bit patterns) / uint-min (negative).
// Requires init to -INFINITY (0xFF800000).
__device__ __forceinline__ void atomicMaxF(float* addr, float val) {
    if (__float_as_int(val) >= 0) {
        atomicMax((int*)addr, __float_as_int(val));
    } else {
        atomicMin((unsigned int*)addr, __float_as_uint(val));
    }
}

// ---------------- init ----------------
__global__ void init_kernel(float* __restrict__ m1, float* __restrict__ s1,
                            float* __restrict__ acc1, float* __restrict__ m2,
                            float* __restrict__ s2, float* __restrict__ acc2,
                            float* __restrict__ out, int N) {
    int stride = gridDim.x * blockDim.x;
    int total = 32 * N;
    for (int idx = blockIdx.x * blockDim.x + threadIdx.x; idx < total; idx += stride) {
        acc1[idx] = 0.f;
        if (idx < 2 * N) { s1[idx] = 0.f; m1[idx] = -INFINITY; }
        if (idx < N)     { s2[idx] = 0.f; acc2[idx] = 0.f; m2[idx] = -INFINITY; }
        if (idx == 0)    out[0] = 0.f;
    }
}

// ---------------- layer 1 GEMM: xp1 = x @ W1, plus a_src/a_dst ----------------
// block = 256 threads, 8 rows/block, thread t -> (row t>>5, col t&31)
__global__ __launch_bounds__(256) void gemm1_kernel(
    const float* __restrict__ x, const float* __restrict__ W1,
    const float* __restrict__ att_src, const float* __restrict__ att_dst,
    float* __restrict__ xp1, float* __restrict__ a_src, float* __restrict__ a_dst,
    int N) {
    __shared__ float wS[128 * 32];
    __shared__ float xS[8 * 128];
    int t = threadIdx.x;
    for (int i = t; i < 128 * 32 / 4; i += 256)
        ((float4*)wS)[i] = ((const float4*)W1)[i];
    int row0 = blockIdx.x * 8;
    int rmax = N - row0;               // rows valid in this block (>=8 normally)
    int lr = t >> 5;                   // float4 index t covers local row t>>5
    if (lr < rmax)
        ((float4*)xS)[t] = ((const float4*)(x + (size_t)row0 * 128))[t];
    __syncthreads();

    int r = t >> 5, col = t & 31;
    int row = row0 + r;
    const float* xrow = xS + r * 128;
    float sum = 0.f;
#pragma unroll 8
    for (int k = 0; k < 128; k++)
        sum = fmaf(xrow[k], wS[k * 32 + col], sum);

    // attention logits: reduce over the 16 channels of each head
    int h = col >> 4;
    float va = sum * att_src[col];     // att[h*16+c] == att[col]
    float vd = sum * att_dst[col];
#pragma unroll
    for (int off = 8; off >= 1; off >>= 1) {
        va += __shfl_xor(va, off);
        vd += __shfl_xor(vd, off);
    }
    if (row < N) {
        xp1[(size_t)row * 32 + col] = sum;
        if ((col & 15) == 0) {
            a_src[row * 2 + h] = va;
            a_dst[row * 2 + h] = vd;
        }
    }
}

// ---------------- layer 1 edge pass A: segment max ----------------
__global__ void edge_l1_max(const int* __restrict__ ei, int E, int N,
                            const float* __restrict__ a_src,
                            const float* __restrict__ a_dst,
                            float* __restrict__ m1) {
    int e = blockIdx.x * blockDim.x + threadIdx.x;
    if (e >= E + N) return;
    int s, d;
    if (e < E) { s = ei[e]; d = ei[E + e]; } else { s = d = e - E; }
#pragma unroll
    for (int h = 0; h < 2; h++) {
        float a = leaky(a_src[s * 2 + h] + a_dst[d * 2 + h]);
        atomicMaxF(&m1[d * 2 + h], a);
    }
}

// ---------------- layer 1 edge pass B: exp + scatter accumulate ----------------
// 8 lanes per edge; lane sub handles channels [sub*4, sub*4+4) (head = sub>>2)
__global__ void edge_l1_acc(const int* __restrict__ ei, int E, int N,
                            const float* __restrict__ a_src,
                            const float* __restrict__ a_dst,
                            const float* __restrict__ m1,
                            const float* __restrict__ xp1,
                            float* __restrict__ s1, float* __restrict__ acc1) {
    int gid = blockIdx.x * blockDim.x + threadIdx.x;
    int e = gid >> 3;
    int sub = gid & 7;
    if (e >= E + N) return;
    int s, d;
    if (e < E) { s = ei[e]; d = ei[E + e]; } else { s = d = e - E; }
    int h = sub >> 2;
    float a = leaky(a_src[s * 2 + h] + a_dst[d * 2 + h]);
    float ex = __expf(a - m1[d * 2 + h]);
    if ((sub & 3) == 0) atomicAdd(&s1[d * 2 + h], ex);
    float4 v = *(const float4*)(xp1 + (size_t)s * 32 + sub * 4);
    float* ap = acc1 + (size_t)d * 32 + sub * 4;
    atomicAdd(ap + 0, ex * v.x);
    atomicAdd(ap + 1, ex * v.y);
    atomicAdd(ap + 2, ex * v.z);
    atomicAdd(ap + 3, ex * v.w);
}

// ---------------- node pass: normalize, +b1, relu, xp2 = h1 @ W2 ----------------
// 32 lanes per node
__global__ void node1_kernel(const float* __restrict__ acc1, const float* __restrict__ s1,
                             const float* __restrict__ b1, const float* __restrict__ W2,
                             float* __restrict__ xp2, int N) {
    int t = blockIdx.x * blockDim.x + threadIdx.x;
    int n = t >> 5;
    int j = t & 31;
    if (n >= N) return;
    float denom = s1[n * 2 + (j >> 4)] + EPS;
    float hv = acc1[(size_t)n * 32 + j] / denom + b1[j];
    hv = hv > 0.f ? hv : 0.f;          // relu
    float p = hv * W2[j];
#pragma unroll
    for (int off = 16; off >= 1; off >>= 1) p += __shfl_xor(p, off);
    if (j == 0) xp2[n] = p;
}

// ---------------- layer 2 edge pass A: segment max ----------------
__global__ void edge_l2_max(const int* __restrict__ ei, int E, int N,
                            const float* __restrict__ xp2,
                            const float* __restrict__ as2p,
                            const float* __restrict__ ad2p,
                            float* __restrict__ m2) {
    int e = blockIdx.x * blockDim.x + threadIdx.x;
    if (e >= E + N) return;
    int s, d;
    if (e < E) { s = ei[e]; d = ei[E + e]; } else { s = d = e - E; }
    float a = leaky(xp2[s] * as2p[0] + xp2[d] * ad2p[0]);
    atomicMaxF(&m2[d], a);
}

// ---------------- layer 2 edge pass B ----------------
__global__ void edge_l2_acc(const int* __restrict__ ei, int E, int N,
                            const float* __restrict__ xp2,
                            const float* __restrict__ as2p,
                            const float* __restrict__ ad2p,
                            const float* __restrict__ m2,
                            float* __restrict__ s2, float* __restrict__ acc2) {
    int e = blockIdx.x * blockDim.x + threadIdx.x;
    if (e >= E + N) return;
    int s, d;
    if (e < E) { s = ei[e]; d = ei[E + e]; } else { s = d = e - E; }
    float a = leaky(xp2[s] * as2p[0] + xp2[d] * ad2p[0]);
    float ex = __expf(a - m2[d]);
    atomicAdd(&s2[d], ex);
    atomicAdd(&acc2[d], ex * xp2[s]);
}

// ---------------- final: out[0] = sum_n acc2[n]/(s2[n]+eps) + b2 ----------------
__global__ void final_kernel(const float* __restrict__ acc2, const float* __restrict__ s2,
                             const float* __restrict__ b2, float* __restrict__ out, int N) {
    int stride = gridDim.x * blockDim.x;
    float sum = 0.f;
    for (int i = blockIdx.x * blockDim.x + threadIdx.x; i < N; i += stride)
        sum += acc2[i] / (s2[i] + EPS) + b2[0];
#pragma unroll
    for (int off = 32; off >= 1; off >>= 1) sum += __shfl_xor(sum, off);
    __shared__ float ls[4];
    int lane = threadIdx.x & 63, w = threadIdx.x >> 6;
    if (lane == 0) ls[w] = sum;
    __syncthreads();
    if (threadIdx.x == 0) atomicAdd(out, ls[0] + ls[1] + ls[2] + ls[3]);
}

extern "C" void kernel_launch(void* const* d_in, const int* in_sizes, int n_in,
                              void* d_out, int out_size, void* d_ws, size_t ws_size,
                              hipStream_t stream) {
    const float* x        = (const float*)d_in[0];
    const int*   ei       = (const int*)d_in[1];
    const float* W1       = (const float*)d_in[2];
    const float* att_src1 = (const float*)d_in[3];
    const float* att_dst1 = (const float*)d_in[4];
    const float* b1       = (const float*)d_in[5];
    const float* W2       = (const float*)d_in[6];
    const float* att_src2 = (const float*)d_in[7];
    const float* att_dst2 = (const float*)d_in[8];
    const float* b2       = (const float*)d_in[9];
    float* out = (float*)d_out;

    int N = in_sizes[0] / 128;
    int E = in_sizes[1] / 2;
    int ET = E + N;

    float* w = (float*)d_ws;
    float* xp1   = w; w += (size_t)N * 32;
    float* a_src = w; w += (size_t)N * 2;
    float* a_dst = w; w += (size_t)N * 2;
    float* m1    = w; w += (size_t)N * 2;
    float* s1    = w; w += (size_t)N * 2;
    float* acc1  = w; w += (size_t)N * 32;
    float* xp2   = w; w += N;
    float* m2    = w; w += N;
    float* s2    = w; w += N;
    float* acc2  = w; w += N;

    init_kernel<<<1024, 256, 0, stream>>>(m1, s1, acc1, m2, s2, acc2, out, N);
    gemm1_kernel<<<(N + 7) / 8, 256, 0, stream>>>(x, W1, att_src1, att_dst1,
                                                  xp1, a_src, a_dst, N);
    edge_l1_max<<<(ET + 255) / 256, 256, 0, stream>>>(ei, E, N, a_src, a_dst, m1);
    edge_l1_acc<<<((ET * 8) + 255) / 256, 256, 0, stream>>>(ei, E, N, a_src, a_dst,
                                                            m1, xp1, s1, acc1);
    node1_kernel<<<(N * 32 + 255) / 256, 256, 0, stream>>>(acc1, s1, b1, W2, xp2, N);
    edge_l2_max<<<(ET + 255) / 256, 256, 0, stream>>>(ei, E, N, xp2, att_src2, att_dst2, m2);
    edge_l2_acc<<<(ET + 255) / 256, 256, 0, stream>>>(ei, E, N, xp2, att_src2, att_dst2,
                                                      m2, s2, acc2);
    final_kernel<<<256, 256, 0, stream>>>(acc2, s2, b2, out, N);
}

// Round 2
// 822.974 us; speedup vs baseline: 2.7373x; 2.7373x over previous
//
#include <hip/hip_runtime.h>
#include <hip/hip_bf16.h>
#include <math.h>

#define NEG_SLOPE 0.2f
#define EPS 1e-16f

__device__ __forceinline__ float leaky(float x) {
    return x > 0.f ? x : NEG_SLOPE * x;
}

// ---------------- init: deg=1 (self loop), out=0 ----------------
__global__ void init_kernel(int* __restrict__ deg, float* __restrict__ out, int N) {
    int i = blockIdx.x * blockDim.x + threadIdx.x;
    if (i < N) deg[i] = 1;
    if (i == 0) out[0] = 0.f;
}

// ---------------- degree histogram over dst ----------------
__global__ void hist_kernel(const int* __restrict__ ei, int E, int* __restrict__ deg) {
    int e = blockIdx.x * blockDim.x + threadIdx.x;
    if (e < E) atomicAdd(&deg[ei[E + e]], 1);
}

// ---------------- 3-kernel exclusive scan ----------------
__global__ void scan_block(const int* __restrict__ in, int* __restrict__ out,
                           int* __restrict__ partials, int n) {
    __shared__ int tmp[256];
    int t = threadIdx.x;
    int g = blockIdx.x * 256 + t;
    int v = (g < n) ? in[g] : 0;
    tmp[t] = v;
    __syncthreads();
    for (int off = 1; off < 256; off <<= 1) {
        int add = (t >= off) ? tmp[t - off] : 0;
        __syncthreads();
        tmp[t] += add;
        __syncthreads();
    }
    if (g < n) out[g] = tmp[t] - v;            // exclusive
    if (t == 255) partials[blockIdx.x] = tmp[255];
}

__global__ void scan_partials(int* __restrict__ partials, int P) {
    __shared__ int tmp[512];
    int t = threadIdx.x;
    int v = (t < P) ? partials[t] : 0;
    tmp[t] = v;
    __syncthreads();
    for (int off = 1; off < 512; off <<= 1) {
        int add = (t >= off) ? tmp[t - off] : 0;
        __syncthreads();
        tmp[t] += add;
        __syncthreads();
    }
    if (t < P) partials[t] = tmp[t] - v;       // exclusive
}

__global__ void scan_add(int* __restrict__ rowptr, int* __restrict__ cursor,
                         const int* __restrict__ partials, int n, int total) {
    int g = blockIdx.x * 256 + threadIdx.x;
    if (g < n) {
        int v = rowptr[g] + partials[blockIdx.x];
        rowptr[g] = v;
        cursor[g] = v;
    }
    if (g == 0) rowptr[n] = total;
}

// ---------------- scatter edges into CSR (src sorted by dst) ----------------
__global__ void scatter_kernel(const int* __restrict__ ei, int E, int N,
                               int* __restrict__ cursor, int* __restrict__ srt) {
    int e = blockIdx.x * blockDim.x + threadIdx.x;
    if (e >= E + N) return;
    int s, d;
    if (e < E) { s = ei[e]; d = ei[E + e]; } else { s = d = e - E; }
    int pos = atomicAdd(&cursor[d], 1);
    srt[pos] = s;
}

// ---------------- layer 1 GEMM: xp1 = x @ W1, plus a_src/a_dst ----------------
__global__ __launch_bounds__(256) void gemm1_kernel(
    const float* __restrict__ x, const float* __restrict__ W1,
    const float* __restrict__ att_src, const float* __restrict__ att_dst,
    float* __restrict__ xp1, float* __restrict__ a_src, float* __restrict__ a_dst,
    int N) {
    __shared__ float wS[128 * 32];
    __shared__ float xS[8 * 128];
    int t = threadIdx.x;
    for (int i = t; i < 128 * 32 / 4; i += 256)
        ((float4*)wS)[i] = ((const float4*)W1)[i];
    int row0 = blockIdx.x * 8;
    int rmax = N - row0;
    int lr = t >> 5;
    if (lr < rmax)
        ((float4*)xS)[t] = ((const float4*)(x + (size_t)row0 * 128))[t];
    __syncthreads();

    int r = t >> 5, col = t & 31;
    int row = row0 + r;
    const float* xrow = xS + r * 128;
    float sum = 0.f;
#pragma unroll 8
    for (int k = 0; k < 128; k++)
        sum = fmaf(xrow[k], wS[k * 32 + col], sum);

    int h = col >> 4;
    float va = sum * att_src[col];
    float vd = sum * att_dst[col];
#pragma unroll
    for (int off = 8; off >= 1; off >>= 1) {
        va += __shfl_xor(va, off);
        vd += __shfl_xor(vd, off);
    }
    if (row < N) {
        xp1[(size_t)row * 32 + col] = sum;
        if ((col & 15) == 0) {
            a_src[row * 2 + h] = va;
            a_dst[row * 2 + h] = vd;
        }
    }
}

// ---------------- fused layer-1 aggregation + normalize + relu + @W2 ----------
// 32 lanes per dst node; lane j owns channel j (head = j>>4).
__global__ __launch_bounds__(256) void agg1_kernel(
    const int* __restrict__ rowptr, const int* __restrict__ srt,
    const float* __restrict__ a_src, const float* __restrict__ a_dst,
    const float* __restrict__ xp1, const float* __restrict__ b1,
    const float* __restrict__ W2, float* __restrict__ xp2, int N) {
    int t = blockIdx.x * blockDim.x + threadIdx.x;
    int n = t >> 5;
    int j = t & 31;
    if (n >= N) return;
    int beg = rowptr[n], end = rowptr[n + 1];
    float ad0 = a_dst[n * 2], ad1 = a_dst[n * 2 + 1];

    // phase 1: segment max, lane-parallel over edges
    float mx0 = -INFINITY, mx1 = -INFINITY;
    for (int i = beg + j; i < end; i += 32) {
        int s = srt[i];
        mx0 = fmaxf(mx0, leaky(a_src[s * 2] + ad0));
        mx1 = fmaxf(mx1, leaky(a_src[s * 2 + 1] + ad1));
    }
#pragma unroll
    for (int off = 16; off >= 1; off >>= 1) {
        mx0 = fmaxf(mx0, __shfl_xor(mx0, off));
        mx1 = fmaxf(mx1, __shfl_xor(mx1, off));
    }

    // phase 2: sequential over edges, lane j owns channel j
    int h = j >> 4;
    float adh = h ? ad1 : ad0;
    float mh = h ? mx1 : mx0;
    float acc = 0.f, ssum = 0.f;
    for (int i = beg; i < end; i++) {
        int s = srt[i];                              // broadcast
        float a = leaky(a_src[s * 2 + h] + adh);
        float ex = __expf(a - mh);
        acc = fmaf(ex, xp1[(size_t)s * 32 + j], acc); // coalesced 128B row
        ssum += ex;
    }
    float hv = acc / (ssum + EPS) + b1[j];
    hv = fmaxf(hv, 0.f);                              // relu
    float p = hv * W2[j];
#pragma unroll
    for (int off = 16; off >= 1; off >>= 1) p += __shfl_xor(p, off);
    if (j == 0) xp2[n] = p;
}

// ---------------- fused layer-2 aggregation + final sum ----------------------
// 32 lanes per node, lane-parallel over edges; block-reduce into out[0].
__global__ __launch_bounds__(256) void agg2_kernel(
    const int* __restrict__ rowptr, const int* __restrict__ srt,
    const float* __restrict__ xp2, const float* __restrict__ as2p,
    const float* __restrict__ ad2p, const float* __restrict__ b2,
    float* __restrict__ out, int N) {
    int t = blockIdx.x * blockDim.x + threadIdx.x;
    int n = t >> 5;
    int j = t & 31;
    float val = 0.f;
    if (n < N) {
        int beg = rowptr[n], end = rowptr[n + 1];
        float as2 = as2p[0], ad2 = ad2p[0];
        float xd = xp2[n] * ad2;
        float mx = -INFINITY;
        for (int i = beg + j; i < end; i += 32)
            mx = fmaxf(mx, leaky(xp2[srt[i]] * as2 + xd));
#pragma unroll
        for (int off = 16; off >= 1; off >>= 1)
            mx = fmaxf(mx, __shfl_xor(mx, off));
        float se = 0.f, sa = 0.f;
        for (int i = beg + j; i < end; i += 32) {
            float xs = xp2[srt[i]];
            float ex = __expf(leaky(xs * as2 + xd) - mx);
            se += ex;
            sa = fmaf(ex, xs, sa);
        }
#pragma unroll
        for (int off = 16; off >= 1; off >>= 1) {
            se += __shfl_xor(se, off);
            sa += __shfl_xor(sa, off);
        }
        if (j == 0) val = sa / (se + EPS) + b2[0];
    }
    // block reduction (val is nonzero only on j==0 lanes)
#pragma unroll
    for (int off = 32; off >= 1; off >>= 1) val += __shfl_xor(val, off);
    __shared__ float ls[4];
    int lane = threadIdx.x & 63, w = threadIdx.x >> 6;
    if (lane == 0) ls[w] = val;
    __syncthreads();
    if (threadIdx.x == 0) atomicAdd(out, ls[0] + ls[1] + ls[2] + ls[3]);
}

extern "C" void kernel_launch(void* const* d_in, const int* in_sizes, int n_in,
                              void* d_out, int out_size, void* d_ws, size_t ws_size,
                              hipStream_t stream) {
    const float* x        = (const float*)d_in[0];
    const int*   ei       = (const int*)d_in[1];
    const float* W1       = (const float*)d_in[2];
    const float* att_src1 = (const float*)d_in[3];
    const float* att_dst1 = (const float*)d_in[4];
    const float* b1       = (const float*)d_in[5];
    const float* W2       = (const float*)d_in[6];
    const float* att_src2 = (const float*)d_in[7];
    const float* att_dst2 = (const float*)d_in[8];
    const float* b2       = (const float*)d_in[9];
    float* out = (float*)d_out;

    int N = in_sizes[0] / 128;
    int E = in_sizes[1] / 2;
    int ET = E + N;
    int nb = (N + 255) / 256;          // scan blocks (391 for N=100K, <=512)

    char* w = (char*)d_ws;
    float* xp1   = (float*)w; w += sizeof(float) * (size_t)N * 32;
    float* a_src = (float*)w; w += sizeof(float) * (size_t)N * 2;
    float* a_dst = (float*)w; w += sizeof(float) * (size_t)N * 2;
    float* xp2   = (float*)w; w += sizeof(float) * (size_t)N;
    int* deg     = (int*)w;   w += sizeof(int) * (size_t)N;
    int* rowptr  = (int*)w;   w += sizeof(int) * (size_t)(N + 1);
    int* cursor  = (int*)w;   w += sizeof(int) * (size_t)N;
    int* partials= (int*)w;   w += sizeof(int) * 512;
    int* srt     = (int*)w;   w += sizeof(int) * (size_t)ET;

    init_kernel<<<nb, 256, 0, stream>>>(deg, out, N);
    hist_kernel<<<(E + 255) / 256, 256, 0, stream>>>(ei, E, deg);
    scan_block<<<nb, 256, 0, stream>>>(deg, rowptr, partials, N);
    scan_partials<<<1, 512, 0, stream>>>(partials, nb);
    scan_add<<<nb, 256, 0, stream>>>(rowptr, cursor, partials, N, ET);
    scatter_kernel<<<(ET + 255) / 256, 256, 0, stream>>>(ei, E, N, cursor, srt);
    gemm1_kernel<<<(N + 7) / 8, 256, 0, stream>>>(x, W1, att_src1, att_dst1,
                                                  xp1, a_src, a_dst, N);
    agg1_kernel<<<(N * 32 + 255) / 256, 256, 0, stream>>>(rowptr, srt, a_src, a_dst,
                                                          xp1, b1, W2, xp2, N);
    agg2_kernel<<<(N * 32 + 255) / 256, 256, 0, stream>>>(rowptr, srt, xp2,
                                                          att_src2, att_dst2, b2, out, N);
}

// Round 3
// 585.497 us; speedup vs baseline: 3.8476x; 1.4056x over previous
//
#include <hip/hip_runtime.h>
#include <hip/hip_bf16.h>
#include <math.h>

#define NEG_SLOPE 0.2f
#define EPS 1e-16f

__device__ __forceinline__ float leaky(float x) {
    return x > 0.f ? x : NEG_SLOPE * x;
}

// ---------------- init: zero deg2 bins, out=0 ----------------
__global__ void initA_kernel(int* __restrict__ deg2, float* __restrict__ out, int M) {
    int i = blockIdx.x * blockDim.x + threadIdx.x;
    if (i < M) deg2[i] = 0;
    if (i == 0) out[0] = 0.f;
}

// ---------------- histogram over (dst, e&7) sub-bins; emit per-edge rank ------
__global__ void hist_rank_kernel(const int* __restrict__ ei, int E, int N,
                                 int* __restrict__ deg2,
                                 unsigned short* __restrict__ rank) {
    int e = blockIdx.x * blockDim.x + threadIdx.x;
    if (e >= E + N) return;
    int d, k;
    if (e < E) { d = ei[E + e]; k = e & 7; } else { d = e - E; k = d & 7; }
    int r = atomicAdd(&deg2[(size_t)d * 8 + k], 1);
    rank[e] = (unsigned short)r;
}

// ---------------- 3-kernel exclusive scan over M = N*8 bins (1024-wide) -------
__global__ void scan_block(const int* __restrict__ in, int* __restrict__ out,
                           int* __restrict__ partials, int n) {
    __shared__ int tmp[1024];
    int t = threadIdx.x;
    int g = blockIdx.x * 1024 + t;
    int v = (g < n) ? in[g] : 0;
    tmp[t] = v;
    __syncthreads();
    for (int off = 1; off < 1024; off <<= 1) {
        int add = (t >= off) ? tmp[t - off] : 0;
        __syncthreads();
        tmp[t] += add;
        __syncthreads();
    }
    if (g < n) out[g] = tmp[t] - v;            // exclusive
    if (t == 1023) partials[blockIdx.x] = tmp[1023];
}

__global__ void scan_partials(int* __restrict__ partials, int P) {
    __shared__ int tmp[1024];
    int t = threadIdx.x;
    int v = (t < P) ? partials[t] : 0;
    tmp[t] = v;
    __syncthreads();
    for (int off = 1; off < 1024; off <<= 1) {
        int add = (t >= off) ? tmp[t - off] : 0;
        __syncthreads();
        tmp[t] += add;
        __syncthreads();
    }
    if (t < P) partials[t] = tmp[t] - v;       // exclusive
}

__global__ void scan_add(int* __restrict__ binptr, const int* __restrict__ partials,
                         int n, int total) {
    int g = blockIdx.x * 1024 + threadIdx.x;
    if (g < n) binptr[g] += partials[blockIdx.x];
    if (g == 0) binptr[n] = total;
}

// ---------------- scatter edges into CSR — atomic-free ----------------
__global__ void scatter2_kernel(const int* __restrict__ ei, int E, int N,
                                const int* __restrict__ binptr,
                                const unsigned short* __restrict__ rank,
                                int* __restrict__ srt) {
    int e = blockIdx.x * blockDim.x + threadIdx.x;
    if (e >= E + N) return;
    int s, d, k;
    if (e < E) { s = ei[e]; d = ei[E + e]; k = e & 7; }
    else       { s = d = e - E; k = d & 7; }
    int pos = binptr[(size_t)d * 8 + k] + (int)rank[e];
    srt[pos] = s;
}

// ---------------- layer 1 GEMM: xp1 = x @ W1, plus a_src/a_dst ----------------
__global__ __launch_bounds__(256) void gemm1_kernel(
    const float* __restrict__ x, const float* __restrict__ W1,
    const float* __restrict__ att_src, const float* __restrict__ att_dst,
    float* __restrict__ xp1, float* __restrict__ a_src, float* __restrict__ a_dst,
    int N) {
    __shared__ float wS[128 * 32];
    __shared__ float xS[8 * 128];
    int t = threadIdx.x;
    for (int i = t; i < 128 * 32 / 4; i += 256)
        ((float4*)wS)[i] = ((const float4*)W1)[i];
    int row0 = blockIdx.x * 8;
    int rmax = N - row0;
    int lr = t >> 5;
    if (lr < rmax)
        ((float4*)xS)[t] = ((const float4*)(x + (size_t)row0 * 128))[t];
    __syncthreads();

    int r = t >> 5, col = t & 31;
    int row = row0 + r;
    const float* xrow = xS + r * 128;
    float sum = 0.f;
#pragma unroll 8
    for (int k = 0; k < 128; k++)
        sum = fmaf(xrow[k], wS[k * 32 + col], sum);

    int h = col >> 4;
    float va = sum * att_src[col];
    float vd = sum * att_dst[col];
#pragma unroll
    for (int off = 8; off >= 1; off >>= 1) {
        va += __shfl_xor(va, off);
        vd += __shfl_xor(vd, off);
    }
    if (row < N) {
        xp1[(size_t)row * 32 + col] = sum;
        if ((col & 15) == 0) {
            a_src[row * 2 + h] = va;
            a_dst[row * 2 + h] = vd;
        }
    }
}

// ---- fused layer-1 aggregation (no max-pass) + normalize + relu + @W2 --------
// 64 lanes per dst node; channel j = lane&31; halves walk alternate edges.
__global__ __launch_bounds__(256) void agg1_kernel(
    const int* __restrict__ binptr, const int* __restrict__ srt,
    const float* __restrict__ a_src, const float* __restrict__ a_dst,
    const float* __restrict__ xp1, const float* __restrict__ b1,
    const float* __restrict__ W2, float* __restrict__ xp2, int N) {
    int t = blockIdx.x * blockDim.x + threadIdx.x;
    int n = t >> 6;
    int lane = t & 63;
    int half = lane >> 5;
    int j = lane & 31;
    if (n >= N) return;
    int beg = binptr[n * 8], end = binptr[n * 8 + 8];
    int h = j >> 4;
    float adh = a_dst[n * 2 + h];

    float acc = 0.f, ssum = 0.f;
    for (int i = beg + half; i < end; i += 2) {
        int s = srt[i];                               // broadcast within half
        float a = leaky(a_src[s * 2 + h] + adh);
        float ex = __expf(a);
        acc = fmaf(ex, xp1[(size_t)s * 32 + j], acc); // coalesced 128B row
        ssum += ex;
    }
    acc  += __shfl_xor(acc, 32);
    ssum += __shfl_xor(ssum, 32);

    float hv = acc / (ssum + EPS) + b1[j];
    hv = fmaxf(hv, 0.f);                              // relu
    float p = hv * W2[j];
#pragma unroll
    for (int off = 16; off >= 1; off >>= 1) p += __shfl_xor(p, off);
    if (lane == 0) xp2[n] = p;
}

// ---- fused layer-2 aggregation (no max-pass) + final sum ---------------------
// 32 lanes per node, lane-parallel over edges; block-reduce into out[0].
__global__ __launch_bounds__(256) void agg2_kernel(
    const int* __restrict__ binptr, const int* __restrict__ srt,
    const float* __restrict__ xp2, const float* __restrict__ as2p,
    const float* __restrict__ ad2p, const float* __restrict__ b2,
    float* __restrict__ out, int N) {
    int t = blockIdx.x * blockDim.x + threadIdx.x;
    int n = t >> 5;
    int j = t & 31;
    float val = 0.f;
    if (n < N) {
        int beg = binptr[n * 8], end = binptr[n * 8 + 8];
        float as2 = as2p[0], ad2 = ad2p[0];
        float xd = xp2[n] * ad2;
        float se = 0.f, sa = 0.f;
        for (int i = beg + j; i < end; i += 32) {
            float xs = xp2[srt[i]];
            float ex = __expf(leaky(xs * as2 + xd));
            se += ex;
            sa = fmaf(ex, xs, sa);
        }
#pragma unroll
        for (int off = 16; off >= 1; off >>= 1) {
            se += __shfl_xor(se, off);
            sa += __shfl_xor(sa, off);
        }
        if (j == 0) val = sa / (se + EPS) + b2[0];
    }
#pragma unroll
    for (int off = 32; off >= 1; off >>= 1) val += __shfl_xor(val, off);
    __shared__ float ls[4];
    int lane = threadIdx.x & 63, w = threadIdx.x >> 6;
    if (lane == 0) ls[w] = val;
    __syncthreads();
    if (threadIdx.x == 0) atomicAdd(out, ls[0] + ls[1] + ls[2] + ls[3]);
}

extern "C" void kernel_launch(void* const* d_in, const int* in_sizes, int n_in,
                              void* d_out, int out_size, void* d_ws, size_t ws_size,
                              hipStream_t stream) {
    const float* x        = (const float*)d_in[0];
    const int*   ei       = (const int*)d_in[1];
    const float* W1       = (const float*)d_in[2];
    const float* att_src1 = (const float*)d_in[3];
    const float* att_dst1 = (const float*)d_in[4];
    const float* b1       = (const float*)d_in[5];
    const float* W2       = (const float*)d_in[6];
    const float* att_src2 = (const float*)d_in[7];
    const float* att_dst2 = (const float*)d_in[8];
    const float* b2       = (const float*)d_in[9];
    float* out = (float*)d_out;

    int N = in_sizes[0] / 128;
    int E = in_sizes[1] / 2;
    int ET = E + N;
    int M  = N * 8;                       // sub-bins
    int nb2 = (M + 1023) / 1024;          // scan blocks (782 for N=100K, <=1024)

    char* w = (char*)d_ws;
    float* xp1    = (float*)w; w += sizeof(float) * (size_t)N * 32;
    float* a_src  = (float*)w; w += sizeof(float) * (size_t)N * 2;
    float* a_dst  = (float*)w; w += sizeof(float) * (size_t)N * 2;
    float* xp2    = (float*)w; w += sizeof(float) * (size_t)N;
    int* binptr   = (int*)w;   w += sizeof(int) * (size_t)(M + 1);
    int* partials = (int*)w;   w += sizeof(int) * 1024;
    int* srt      = (int*)w;   w += sizeof(int) * (size_t)ET;
    unsigned short* rank = (unsigned short*)w; w += sizeof(unsigned short) * (size_t)ET;
    int* deg2     = (int*)w;   w += sizeof(int) * (size_t)M;   // scan input

    initA_kernel<<<(M + 255) / 256, 256, 0, stream>>>(deg2, out, M);
    hist_rank_kernel<<<(ET + 255) / 256, 256, 0, stream>>>(ei, E, N, deg2, rank);
    scan_block<<<nb2, 1024, 0, stream>>>(deg2, binptr, partials, M);
    scan_partials<<<1, 1024, 0, stream>>>(partials, nb2);
    scan_add<<<nb2, 1024, 0, stream>>>(binptr, partials, M, ET);
    scatter2_kernel<<<(ET + 255) / 256, 256, 0, stream>>>(ei, E, N, binptr, rank, srt);
    gemm1_kernel<<<(N + 7) / 8, 256, 0, stream>>>(x, W1, att_src1, att_dst1,
                                                  xp1, a_src, a_dst, N);
    agg1_kernel<<<(N * 64 + 255) / 256, 256, 0, stream>>>(binptr, srt, a_src, a_dst,
                                                          xp1, b1, W2, xp2, N);
    agg2_kernel<<<(N * 32 + 255) / 256, 256, 0, stream>>>(binptr, srt, xp2,
                                                          att_src2, att_dst2, b2, out, N);
}

// Round 4
// 441.114 us; speedup vs baseline: 5.1069x; 1.3273x over previous
//
#include <hip/hip_runtime.h>
#include <hip/hip_bf16.h>
#include <hip/hip_fp16.h>
#include <math.h>

#define NEG_SLOPE 0.2f
#define EPS 1e-16f

__device__ __forceinline__ float leaky(float x) {
    return x > 0.f ? x : NEG_SLOPE * x;
}

// ---------------- init: zero deg2 bins ----------------
__global__ void initA_kernel(int* __restrict__ deg2, int M) {
    int i = blockIdx.x * blockDim.x + threadIdx.x;
    if (i < M) deg2[i] = 0;
}

// ---------------- histogram over (dst, e&7) sub-bins; emit per-edge rank ------
__global__ void hist_rank_kernel(const int* __restrict__ ei, int E, int N,
                                 int* __restrict__ deg2,
                                 unsigned short* __restrict__ rank) {
    int e = blockIdx.x * blockDim.x + threadIdx.x;
    if (e >= E + N) return;
    int d, k;
    if (e < E) { d = ei[E + e]; k = e & 7; } else { d = e - E; k = d & 7; }
    int r = atomicAdd(&deg2[(size_t)d * 8 + k], 1);
    rank[e] = (unsigned short)r;
}

// ---------------- 3-kernel exclusive scan over M = N*8 bins (1024-wide) -------
__global__ void scan_block(const int* __restrict__ in, int* __restrict__ out,
                           int* __restrict__ partials, int n) {
    __shared__ int tmp[1024];
    int t = threadIdx.x;
    int g = blockIdx.x * 1024 + t;
    int v = (g < n) ? in[g] : 0;
    tmp[t] = v;
    __syncthreads();
    for (int off = 1; off < 1024; off <<= 1) {
        int add = (t >= off) ? tmp[t - off] : 0;
        __syncthreads();
        tmp[t] += add;
        __syncthreads();
    }
    if (g < n) out[g] = tmp[t] - v;            // exclusive
    if (t == 1023) partials[blockIdx.x] = tmp[1023];
}

__global__ void scan_partials(int* __restrict__ partials, int P) {
    __shared__ int tmp[1024];
    int t = threadIdx.x;
    int v = (t < P) ? partials[t] : 0;
    tmp[t] = v;
    __syncthreads();
    for (int off = 1; off < 1024; off <<= 1) {
        int add = (t >= off) ? tmp[t - off] : 0;
        __syncthreads();
        tmp[t] += add;
        __syncthreads();
    }
    if (t < P) partials[t] = tmp[t] - v;       // exclusive
}

__global__ void scan_add(int* __restrict__ binptr, const int* __restrict__ partials,
                         int n, int total) {
    int g = blockIdx.x * 1024 + threadIdx.x;
    if (g < n) binptr[g] += partials[blockIdx.x];
    if (g == 0) binptr[n] = total;
}

// ---------------- scatter edges into CSR — atomic-free ----------------
__global__ void scatter2_kernel(const int* __restrict__ ei, int E, int N,
                                const int* __restrict__ binptr,
                                const unsigned short* __restrict__ rank,
                                int* __restrict__ srt) {
    int e = blockIdx.x * blockDim.x + threadIdx.x;
    if (e >= E + N) return;
    int s, d, k;
    if (e < E) { s = ei[e]; d = ei[E + e]; k = e & 7; }
    else       { s = d = e - E; k = d & 7; }
    int pos = binptr[(size_t)d * 8 + k] + (int)rank[e];
    srt[pos] = s;
}

// ---------------- layer 1 GEMM: xp1 (fp16) = x @ W1, plus a_src/a_dst ---------
__global__ __launch_bounds__(256) void gemm1_kernel(
    const float* __restrict__ x, const float* __restrict__ W1,
    const float* __restrict__ att_src, const float* __restrict__ att_dst,
    __half* __restrict__ xp1h, float* __restrict__ a_src, float* __restrict__ a_dst,
    int N) {
    __shared__ float wS[128 * 32];
    __shared__ float xS[8 * 128];
    int t = threadIdx.x;
    for (int i = t; i < 128 * 32 / 4; i += 256)
        ((float4*)wS)[i] = ((const float4*)W1)[i];
    int row0 = blockIdx.x * 8;
    int rmax = N - row0;
    int lr = t >> 5;
    if (lr < rmax)
        ((float4*)xS)[t] = ((const float4*)(x + (size_t)row0 * 128))[t];
    __syncthreads();

    int r = t >> 5, col = t & 31;
    int row = row0 + r;
    const float* xrow = xS + r * 128;
    float sum = 0.f;
#pragma unroll 8
    for (int k = 0; k < 128; k++)
        sum = fmaf(xrow[k], wS[k * 32 + col], sum);

    int h = col >> 4;
    float va = sum * att_src[col];
    float vd = sum * att_dst[col];
#pragma unroll
    for (int off = 8; off >= 1; off >>= 1) {
        va += __shfl_xor(va, off);
        vd += __shfl_xor(vd, off);
    }
    if (row < N) {
        xp1h[(size_t)row * 32 + col] = __float2half(sum);
        if ((col & 15) == 0) {
            a_src[row * 2 + h] = va;
            a_dst[row * 2 + h] = vd;
        }
    }
}

// ---- fused layer-1 aggregation (no max-pass) + normalize + relu + @W2 --------
// 64 lanes per dst node; channel j = lane&31; halves walk alternate edges.
__global__ __launch_bounds__(256) void agg1_kernel(
    const int* __restrict__ binptr, const int* __restrict__ srt,
    const float* __restrict__ a_src, const float* __restrict__ a_dst,
    const __half* __restrict__ xp1h, const float* __restrict__ b1,
    const float* __restrict__ W2, float* __restrict__ xp2, int N) {
    int t = blockIdx.x * blockDim.x + threadIdx.x;
    int n = t >> 6;
    int lane = t & 63;
    int half = lane >> 5;
    int j = lane & 31;
    if (n >= N) return;
    int beg = binptr[n * 8], end = binptr[n * 8 + 8];
    int h = j >> 4;
    float adh = a_dst[n * 2 + h];

    float acc = 0.f, ssum = 0.f;
    for (int i = beg + half; i < end; i += 2) {
        int s = srt[i];                               // broadcast within half
        float a = leaky(a_src[s * 2 + h] + adh);
        float ex = __expf(a);
        float xv = __half2float(xp1h[(size_t)s * 32 + j]);  // coalesced 64B row
        acc = fmaf(ex, xv, acc);
        ssum += ex;
    }
    acc  += __shfl_xor(acc, 32);
    ssum += __shfl_xor(ssum, 32);

    float hv = acc / (ssum + EPS) + b1[j];
    hv = fmaxf(hv, 0.f);                              // relu
    float p = hv * W2[j];
#pragma unroll
    for (int off = 16; off >= 1; off >>= 1) p += __shfl_xor(p, off);
    if (lane == 0) xp2[n] = p;
}

// ---- fused layer-2 aggregation: grid-stride, per-block partial sums ----------
// 32-lane slot per node; 2 slots per wave; no global atomics.
__global__ __launch_bounds__(256) void agg2_kernel(
    const int* __restrict__ binptr, const int* __restrict__ srt,
    const float* __restrict__ xp2, const float* __restrict__ as2p,
    const float* __restrict__ ad2p, const float* __restrict__ b2,
    float* __restrict__ partial, int N) {
    int slot = (blockIdx.x * blockDim.x + threadIdx.x) >> 5;
    int j = threadIdx.x & 31;
    int nslots = (gridDim.x * blockDim.x) >> 5;
    float as2 = as2p[0], ad2 = ad2p[0], bb = b2[0];
    float val = 0.f;
    for (int n = slot; n < N; n += nslots) {
        int beg = binptr[n * 8], end = binptr[n * 8 + 8];
        float xd = xp2[n] * ad2;
        float se = 0.f, sa = 0.f;
        for (int i = beg + j; i < end; i += 32) {
            float xs = xp2[srt[i]];
            float ex = __expf(leaky(xs * as2 + xd));
            se += ex;
            sa = fmaf(ex, xs, sa);
        }
#pragma unroll
        for (int off = 16; off >= 1; off >>= 1) {
            se += __shfl_xor(se, off);
            sa += __shfl_xor(sa, off);
        }
        if (j == 0) val += sa / (se + EPS) + bb;
    }
    // val nonzero only on j==0 lanes; full 64-lane sum then LDS across waves
#pragma unroll
    for (int off = 32; off >= 1; off >>= 1) val += __shfl_xor(val, off);
    __shared__ float ls[4];
    int lane = threadIdx.x & 63, w = threadIdx.x >> 6;
    if (lane == 0) ls[w] = val;
    __syncthreads();
    if (threadIdx.x == 0) partial[blockIdx.x] = ls[0] + ls[1] + ls[2] + ls[3];
}

// ---------------- final: out[0] = sum of partials ----------------
__global__ void final_reduce(const float* __restrict__ partial, float* __restrict__ out,
                             int P) {
    int t = threadIdx.x;
    float v = 0.f;
    for (int i = t; i < P; i += 1024) v += partial[i];
#pragma unroll
    for (int off = 32; off >= 1; off >>= 1) v += __shfl_xor(v, off);
    __shared__ float ls[16];
    int w = t >> 6, lane = t & 63;
    if (lane == 0) ls[w] = v;
    __syncthreads();
    if (t == 0) {
        float s = 0.f;
        for (int i = 0; i < 16; i++) s += ls[i];
        out[0] = s;
    }
}

extern "C" void kernel_launch(void* const* d_in, const int* in_sizes, int n_in,
                              void* d_out, int out_size, void* d_ws, size_t ws_size,
                              hipStream_t stream) {
    const float* x        = (const float*)d_in[0];
    const int*   ei       = (const int*)d_in[1];
    const float* W1       = (const float*)d_in[2];
    const float* att_src1 = (const float*)d_in[3];
    const float* att_dst1 = (const float*)d_in[4];
    const float* b1       = (const float*)d_in[5];
    const float* W2       = (const float*)d_in[6];
    const float* att_src2 = (const float*)d_in[7];
    const float* att_dst2 = (const float*)d_in[8];
    const float* b2       = (const float*)d_in[9];
    float* out = (float*)d_out;

    int N = in_sizes[0] / 128;
    int E = in_sizes[1] / 2;
    int ET = E + N;
    int M  = N * 8;                       // sub-bins
    int nb2 = (M + 1023) / 1024;          // scan blocks (782 for N=100K, <=1024)
    const int AGG2_BLOCKS = 2048;

    char* w = (char*)d_ws;
    __half* xp1h  = (__half*)w; w += sizeof(__half) * (size_t)N * 32;
    float* a_src  = (float*)w; w += sizeof(float) * (size_t)N * 2;
    float* a_dst  = (float*)w; w += sizeof(float) * (size_t)N * 2;
    float* xp2    = (float*)w; w += sizeof(float) * (size_t)N;
    int* binptr   = (int*)w;   w += sizeof(int) * (size_t)(M + 1);
    int* partials = (int*)w;   w += sizeof(int) * 1024;
    float* part2  = (float*)w; w += sizeof(float) * AGG2_BLOCKS;
    int* srt      = (int*)w;   w += sizeof(int) * (size_t)ET;
    unsigned short* rank = (unsigned short*)w; w += sizeof(unsigned short) * (size_t)ET;
    int* deg2     = (int*)w;   w += sizeof(int) * (size_t)M;   // scan input

    initA_kernel<<<(M + 255) / 256, 256, 0, stream>>>(deg2, M);
    hist_rank_kernel<<<(ET + 255) / 256, 256, 0, stream>>>(ei, E, N, deg2, rank);
    scan_block<<<nb2, 1024, 0, stream>>>(deg2, binptr, partials, M);
    scan_partials<<<1, 1024, 0, stream>>>(partials, nb2);
    scan_add<<<nb2, 1024, 0, stream>>>(binptr, partials, M, ET);
    scatter2_kernel<<<(ET + 255) / 256, 256, 0, stream>>>(ei, E, N, binptr, rank, srt);
    gemm1_kernel<<<(N + 7) / 8, 256, 0, stream>>>(x, W1, att_src1, att_dst1,
                                                  xp1h, a_src, a_dst, N);
    agg1_kernel<<<(N * 64 + 255) / 256, 256, 0, stream>>>(binptr, srt, a_src, a_dst,
                                                          xp1h, b1, W2, xp2, N);
    agg2_kernel<<<AGG2_BLOCKS, 256, 0, stream>>>(binptr, srt, xp2,
                                                 att_src2, att_dst2, b2, part2, N);
    final_reduce<<<1, 1024, 0, stream>>>(part2, out, AGG2_BLOCKS);
}

// Round 5
// 347.644 us; speedup vs baseline: 6.4800x; 1.2689x over previous
//
#include <hip/hip_runtime.h>
#include <hip/hip_bf16.h>
#include <hip/hip_fp16.h>
#include <math.h>

#define NEG_SLOPE 0.2f
#define EPS 1e-16f

__device__ __forceinline__ float leaky(float x) {
    return x > 0.f ? x : NEG_SLOPE * x;
}

// ---------------- init: zero deg2 bins ----------------
__global__ void initA_kernel(int* __restrict__ deg2, int M) {
    int i = blockIdx.x * blockDim.x + threadIdx.x;
    if (i < M) deg2[i] = 0;
}

// ---------------- histogram over (dst, e&7) sub-bins; emit per-edge rank ------
__global__ void hist_rank_kernel(const int* __restrict__ ei, int E, int N,
                                 int* __restrict__ deg2,
                                 unsigned short* __restrict__ rank) {
    int e = blockIdx.x * blockDim.x + threadIdx.x;
    if (e >= E + N) return;
    int d, k;
    if (e < E) { d = ei[E + e]; k = e & 7; } else { d = e - E; k = d & 7; }
    int r = atomicAdd(&deg2[(size_t)d * 8 + k], 1);
    rank[e] = (unsigned short)r;
}

// ---------------- 3-kernel exclusive scan over M = N*8 bins (1024-wide) -------
__global__ void scan_block(const int* __restrict__ in, int* __restrict__ out,
                           int* __restrict__ partials, int n) {
    __shared__ int tmp[1024];
    int t = threadIdx.x;
    int g = blockIdx.x * 1024 + t;
    int v = (g < n) ? in[g] : 0;
    tmp[t] = v;
    __syncthreads();
    for (int off = 1; off < 1024; off <<= 1) {
        int add = (t >= off) ? tmp[t - off] : 0;
        __syncthreads();
        tmp[t] += add;
        __syncthreads();
    }
    if (g < n) out[g] = tmp[t] - v;            // exclusive
    if (t == 1023) partials[blockIdx.x] = tmp[1023];
}

__global__ void scan_partials(int* __restrict__ partials, int P) {
    __shared__ int tmp[1024];
    int t = threadIdx.x;
    int v = (t < P) ? partials[t] : 0;
    tmp[t] = v;
    __syncthreads();
    for (int off = 1; off < 1024; off <<= 1) {
        int add = (t >= off) ? tmp[t - off] : 0;
        __syncthreads();
        tmp[t] += add;
        __syncthreads();
    }
    if (t < P) partials[t] = tmp[t] - v;       // exclusive
}

__global__ void scan_add(int* __restrict__ binptr, const int* __restrict__ partials,
                         int n, int total) {
    int g = blockIdx.x * 1024 + threadIdx.x;
    if (g < n) binptr[g] += partials[blockIdx.x];
    if (g == 0) binptr[n] = total;
}

// ---------------- scatter edges into CSR — atomic-free ----------------
__global__ void scatter2_kernel(const int* __restrict__ ei, int E, int N,
                                const int* __restrict__ binptr,
                                const unsigned short* __restrict__ rank,
                                int* __restrict__ srt) {
    int e = blockIdx.x * blockDim.x + threadIdx.x;
    if (e >= E + N) return;
    int s, d, k;
    if (e < E) { s = ei[e]; d = ei[E + e]; k = e & 7; }
    else       { s = d = e - E; k = d & 7; }
    int pos = binptr[(size_t)d * 8 + k] + (int)rank[e];
    srt[pos] = s;
}

// ---------------- layer 1 GEMM: xp1 (fp16) = x @ W1, plus a_src/a_dst ---------
__global__ __launch_bounds__(256) void gemm1_kernel(
    const float* __restrict__ x, const float* __restrict__ W1,
    const float* __restrict__ att_src, const float* __restrict__ att_dst,
    __half* __restrict__ xp1h, float* __restrict__ a_src, float* __restrict__ a_dst,
    int N) {
    __shared__ float wS[128 * 32];
    __shared__ float xS[8 * 128];
    int t = threadIdx.x;
    for (int i = t; i < 128 * 32 / 4; i += 256)
        ((float4*)wS)[i] = ((const float4*)W1)[i];
    int row0 = blockIdx.x * 8;
    int rmax = N - row0;
    int lr = t >> 5;
    if (lr < rmax)
        ((float4*)xS)[t] = ((const float4*)(x + (size_t)row0 * 128))[t];
    __syncthreads();

    int r = t >> 5, col = t & 31;
    int row = row0 + r;
    const float* xrow = xS + r * 128;
    float sum = 0.f;
#pragma unroll 8
    for (int k = 0; k < 128; k++)
        sum = fmaf(xrow[k], wS[k * 32 + col], sum);

    int h = col >> 4;
    float va = sum * att_src[col];
    float vd = sum * att_dst[col];
#pragma unroll
    for (int off = 8; off >= 1; off >>= 1) {
        va += __shfl_xor(va, off);
        vd += __shfl_xor(vd, off);
    }
    if (row < N) {
        xp1h[(size_t)row * 32 + col] = __float2half(sum);
        if ((col & 15) == 0) {
            a_src[row * 2 + h] = va;
            a_dst[row * 2 + h] = vd;
        }
    }
}

// ---- fused layer-1 aggregation + normalize + relu + @W2 ----------------------
// 64 lanes per dst node; channel j = lane&31; LDS-staged edge data for MLP.
// Stage phase: lane L loads edge i0+L (coalesced srt, gathered a_src float2,
// exp computed once per edge) -> LDS float4 (s, e0, e1, -).
// Compute phase: half `half` walks staged slots of parity `half` (broadcast
// ds_read_b128), gathers the 64B xp1h row, unrolled 4x for in-flight gathers.
__global__ __launch_bounds__(256) void agg1_kernel(
    const int* __restrict__ binptr, const int* __restrict__ srt,
    const float2* __restrict__ a_src2, const float2* __restrict__ a_dst2,
    const __half* __restrict__ xp1h, const float* __restrict__ b1,
    const float* __restrict__ W2, float* __restrict__ xp2, int N) {
    __shared__ float4 stage[4][64];
    int t = blockIdx.x * blockDim.x + threadIdx.x;
    int n = t >> 6;
    int lane = threadIdx.x & 63;
    int wib = threadIdx.x >> 6;
    int half = lane >> 5;
    int j = lane & 31;
    if (n >= N) return;
    int beg = binptr[n * 8], end = binptr[n * 8 + 8];
    float2 ad = a_dst2[n];
    int h = j >> 4;

    float acc = 0.f, ssum = 0.f;
    for (int i0 = beg; i0 < end; i0 += 64) {
        int cw = end - i0;                       // edges in this chunk (may be >64 logically; clamp)
        if (cw > 64) cw = 64;
        if (lane < cw) {
            int s = srt[i0 + lane];
            float2 as = a_src2[s];
            float e0 = __expf(leaky(as.x + ad.x));
            float e1 = __expf(leaky(as.y + ad.y));
            stage[wib][lane] = make_float4(__int_as_float(s), e0, e1, 0.f);
        }
        // half walks parity-interleaved slots: half, half+2, ...
        int cntH = (cw - half + 1) >> 1;
#pragma unroll 4
        for (int k = 0; k < cntH; k++) {
            float4 st = stage[wib][2 * k + half];
            int sk = __float_as_int(st.x);
            float ek = h ? st.z : st.y;
            float xv = __half2float(xp1h[(size_t)sk * 32 + j]);
            acc = fmaf(ek, xv, acc);
            ssum += ek;
        }
    }
    acc  += __shfl_xor(acc, 32);
    ssum += __shfl_xor(ssum, 32);

    float hv = acc / (ssum + EPS) + b1[j];
    hv = fmaxf(hv, 0.f);                          // relu
    float p = hv * W2[j];
#pragma unroll
    for (int off = 16; off >= 1; off >>= 1) p += __shfl_xor(p, off);
    if (lane == 0) xp2[n] = p;
}

// ---- fused layer-2 aggregation: grid-stride, per-block partial sums ----------
__global__ __launch_bounds__(256) void agg2_kernel(
    const int* __restrict__ binptr, const int* __restrict__ srt,
    const float* __restrict__ xp2, const float* __restrict__ as2p,
    const float* __restrict__ ad2p, const float* __restrict__ b2,
    float* __restrict__ partial, int N) {
    int slot = (blockIdx.x * blockDim.x + threadIdx.x) >> 5;
    int j = threadIdx.x & 31;
    int nslots = (gridDim.x * blockDim.x) >> 5;
    float as2 = as2p[0], ad2 = ad2p[0], bb = b2[0];
    float val = 0.f;
    for (int n = slot; n < N; n += nslots) {
        int beg = binptr[n * 8], end = binptr[n * 8 + 8];
        float xd = xp2[n] * ad2;
        float se = 0.f, sa = 0.f;
        for (int i = beg + j; i < end; i += 32) {
            float xs = xp2[srt[i]];
            float ex = __expf(leaky(xs * as2 + xd));
            se += ex;
            sa = fmaf(ex, xs, sa);
        }
#pragma unroll
        for (int off = 16; off >= 1; off >>= 1) {
            se += __shfl_xor(se, off);
            sa += __shfl_xor(sa, off);
        }
        if (j == 0) val += sa / (se + EPS) + bb;
    }
#pragma unroll
    for (int off = 32; off >= 1; off >>= 1) val += __shfl_xor(val, off);
    __shared__ float ls[4];
    int lane = threadIdx.x & 63, w = threadIdx.x >> 6;
    if (lane == 0) ls[w] = val;
    __syncthreads();
    if (threadIdx.x == 0) partial[blockIdx.x] = ls[0] + ls[1] + ls[2] + ls[3];
}

// ---------------- final: out[0] = sum of partials ----------------
__global__ void final_reduce(const float* __restrict__ partial, float* __restrict__ out,
                             int P) {
    int t = threadIdx.x;
    float v = 0.f;
    for (int i = t; i < P; i += 1024) v += partial[i];
#pragma unroll
    for (int off = 32; off >= 1; off >>= 1) v += __shfl_xor(v, off);
    __shared__ float ls[16];
    int w = t >> 6, lane = t & 63;
    if (lane == 0) ls[w] = v;
    __syncthreads();
    if (t == 0) {
        float s = 0.f;
        for (int i = 0; i < 16; i++) s += ls[i];
        out[0] = s;
    }
}

extern "C" void kernel_launch(void* const* d_in, const int* in_sizes, int n_in,
                              void* d_out, int out_size, void* d_ws, size_t ws_size,
                              hipStream_t stream) {
    const float* x        = (const float*)d_in[0];
    const int*   ei       = (const int*)d_in[1];
    const float* W1       = (const float*)d_in[2];
    const float* att_src1 = (const float*)d_in[3];
    const float* att_dst1 = (const float*)d_in[4];
    const float* b1       = (const float*)d_in[5];
    const float* W2       = (const float*)d_in[6];
    const float* att_src2 = (const float*)d_in[7];
    const float* att_dst2 = (const float*)d_in[8];
    const float* b2       = (const float*)d_in[9];
    float* out = (float*)d_out;

    int N = in_sizes[0] / 128;
    int E = in_sizes[1] / 2;
    int ET = E + N;
    int M  = N * 8;                       // sub-bins
    int nb2 = (M + 1023) / 1024;          // scan blocks (782 for N=100K, <=1024)
    const int AGG2_BLOCKS = 2048;

    char* w = (char*)d_ws;
    __half* xp1h  = (__half*)w; w += sizeof(__half) * (size_t)N * 32;
    float* a_src  = (float*)w; w += sizeof(float) * (size_t)N * 2;
    float* a_dst  = (float*)w; w += sizeof(float) * (size_t)N * 2;
    float* xp2    = (float*)w; w += sizeof(float) * (size_t)N;
    int* binptr   = (int*)w;   w += sizeof(int) * (size_t)(M + 1);
    int* partials = (int*)w;   w += sizeof(int) * 1024;
    float* part2  = (float*)w; w += sizeof(float) * AGG2_BLOCKS;
    int* srt      = (int*)w;   w += sizeof(int) * (size_t)ET;
    unsigned short* rank = (unsigned short*)w; w += sizeof(unsigned short) * (size_t)ET;
    int* deg2     = (int*)w;   w += sizeof(int) * (size_t)M;   // scan input

    initA_kernel<<<(M + 255) / 256, 256, 0, stream>>>(deg2, M);
    hist_rank_kernel<<<(ET + 255) / 256, 256, 0, stream>>>(ei, E, N, deg2, rank);
    scan_block<<<nb2, 1024, 0, stream>>>(deg2, binptr, partials, M);
    scan_partials<<<1, 1024, 0, stream>>>(partials, nb2);
    scan_add<<<nb2, 1024, 0, stream>>>(binptr, partials, M, ET);
    scatter2_kernel<<<(ET + 255) / 256, 256, 0, stream>>>(ei, E, N, binptr, rank, srt);
    gemm1_kernel<<<(N + 7) / 8, 256, 0, stream>>>(x, W1, att_src1, att_dst1,
                                                  xp1h, a_src, a_dst, N);
    agg1_kernel<<<(N * 64 + 255) / 256, 256, 0, stream>>>(binptr, srt,
                                                          (const float2*)a_src,
                                                          (const float2*)a_dst,
                                                          xp1h, b1, W2, xp2, N);
    agg2_kernel<<<AGG2_BLOCKS, 256, 0, stream>>>(binptr, srt, xp2,
                                                 att_src2, att_dst2, b2, part2, N);
    final_reduce<<<1, 1024, 0, stream>>>(part2, out, AGG2_BLOCKS);
}